// Round 1
// baseline (665.302 us; speedup 1.0000x reference)
//
#include <hip/hip_runtime.h>
#include <hip/hip_bf16.h>
#include <math.h>

// Problem constants (B=4, N=2048, D=1024, E=8, H=4096, C = int(2048*1.25//8)=320)
#define B_ 4
#define N_ 2048
#define D_ 1024
#define E_ 8
#define H_ 4096
#define C_ 320
#define M_ (B_*C_)        // 1280 rows per expert in the grouped GEMMs

typedef __attribute__((ext_vector_type(8))) short short8;   // 8 bf16 = 4 VGPRs (MFMA A/B frag)
typedef __attribute__((ext_vector_type(4))) float floatx4;  // MFMA C/D frag

__device__ __forceinline__ unsigned short f2bf(float f) {
  unsigned u = __builtin_bit_cast(unsigned, f);
  u += 0x7fffu + ((u >> 16) & 1u);          // RNE; inputs are tame (no NaN/Inf)
  return (unsigned short)(u >> 16);
}

// fast tanh-gelu via v_exp_f32: tanh(u) = 1 - 2/(exp(2u)+1). |err| ~1e-6, buried by bf16.
__device__ __forceinline__ float gelu_fast(float x) {
  float u = 0.7978845608028654f * (x + 0.044715f * x * x * x);
  float t = 1.f - 2.f / (__expf(2.f * u) + 1.f);
  return 0.5f * x * (1.f + t);
}

// async global -> LDS, 16 B per lane. LDS dest = wave-uniform base + lane*16 (m97/m104).
__device__ __forceinline__ void gload_lds16(const unsigned short* g, unsigned short* l) {
  __builtin_amdgcn_global_load_lds(
      (const __attribute__((address_space(1))) unsigned int*)g,
      (__attribute__((address_space(3))) unsigned int*)l, 16, 0, 0);
}

// ---------------------------------------------------------------------------
// K1: router. One wave per token; fp64 accumulation to avoid argmax flips vs
// the numpy fp32 reference. stats: [0..31]=count[b*8+e], [32..63]=proxy, [64]=z^2 sum
// ---------------------------------------------------------------------------
__global__ __launch_bounds__(256) void router_kernel(
    const float* __restrict__ x, const float* __restrict__ wr,
    int* __restrict__ idx_buf, float* __restrict__ gate_buf,
    float* __restrict__ stats)
{
  int lane  = threadIdx.x & 63;
  int wave  = threadIdx.x >> 6;
  int token = blockIdx.x * 4 + wave;        // 0..8191
  int b     = token >> 11;                  // N_=2048

  const float* xp = x + (size_t)token * D_ + lane * 16;
  float xv[16];
#pragma unroll
  for (int i = 0; i < 4; i++) {
    float4 v = ((const float4*)xp)[i];
    xv[i*4+0]=v.x; xv[i*4+1]=v.y; xv[i*4+2]=v.z; xv[i*4+3]=v.w;
  }
  double acc[8];
#pragma unroll
  for (int e = 0; e < 8; e++) acc[e] = 0.0;
  const float* wp = wr + (size_t)(lane * 16) * E_;   // w_router is [D][E]
#pragma unroll
  for (int i = 0; i < 16; i++) {
    float xs = xv[i];
#pragma unroll
    for (int e = 0; e < 8; e++) acc[e] += (double)xs * (double)wp[i*8 + e];
  }
  for (int off = 32; off > 0; off >>= 1) {
#pragma unroll
    for (int e = 0; e < 8; e++) acc[e] += __shfl_xor(acc[e], off, 64);
  }

  float l[8];
#pragma unroll
  for (int e = 0; e < 8; e++) l[e] = (float)acc[e];
  float m = l[0]; int best = 0;
#pragma unroll
  for (int e = 1; e < 8; e++) if (l[e] > m) { m = l[e]; best = e; }   // first-max tiebreak
  float p[8], sum = 0.f;
#pragma unroll
  for (int e = 0; e < 8; e++) { p[e] = expf(l[e] - m); sum += p[e]; }
  float inv = 1.f / sum;
#pragma unroll
  for (int e = 0; e < 8; e++) p[e] *= inv;
  float z    = m + logf(sum);
  float gate = inv;                      // softmax at argmax = exp(0)/sum

  __shared__ float s_cnt[8], s_prox[8], s_zsq[1];
  if (threadIdx.x < 8)  { s_cnt[threadIdx.x] = 0.f; s_prox[threadIdx.x] = 0.f; }
  if (threadIdx.x == 8) s_zsq[0] = 0.f;
  __syncthreads();
  if (lane == 0) {
    idx_buf[token]  = best;
    gate_buf[token] = gate;
    atomicAdd(&s_zsq[0], z * z);
    atomicAdd(&s_cnt[best], 1.f);
#pragma unroll
    for (int e = 0; e < 8; e++) atomicAdd(&s_prox[e], p[e]);
  }
  __syncthreads();
  if (threadIdx.x < 8) {
    atomicAdd(&stats[b*8 + threadIdx.x],      s_cnt[threadIdx.x]);
    atomicAdd(&stats[32 + b*8 + threadIdx.x], s_prox[threadIdx.x]);
  }
  if (threadIdx.x == 8) atomicAdd(&stats[64], s_zsq[0]);
}

// ---------------------------------------------------------------------------
// K2: per-(b,e) capacity scan + loss finalize (folded; stats ready since the
// router kernel completed before this launch).
// ---------------------------------------------------------------------------
__global__ __launch_bounds__(64) void pos_kernel(
    const int* __restrict__ idx_buf, int* __restrict__ slot_token,
    const float* __restrict__ stats, float* __restrict__ loss_out)
{
  int be = blockIdx.x;                 // 0..31
  int b = be >> 3, e = be & 7;
  int lane = threadIdx.x;
  int base = 0;
  int* out = slot_token + (size_t)(e * B_ + b) * C_;
  for (int n0 = 0; n0 < N_; n0 += 64) {
    int n = n0 + lane;
    bool match = (idx_buf[b * N_ + n] == e);
    unsigned long long mask = __ballot(match);
    int my = base + __popcll(mask & ((1ull << lane) - 1ull));
    if (match && my < C_) out[my] = b * N_ + n;
    base += __popcll(mask);
  }
  if (be == 0 && lane == 0) {
    float aux = 0.f;
    for (int i = 0; i < 32; i++) aux += stats[i] * stats[32 + i];
    aux *= 64.f / ((float)B_ * (float)N_ * (float)N_);   // E^2 / (B*N*N)
    loss_out[0] = aux;
    loss_out[1] = stats[64] / (float)(B_ * N_);
  }
}

// ---------------------------------------------------------------------------
// K3: gather+cast x rows into xe bf16 [E][M_][D]. One block per slot row.
// ---------------------------------------------------------------------------
__global__ __launch_bounds__(256) void gather_kernel(
    const float* __restrict__ x, const int* __restrict__ slot_token,
    unsigned short* __restrict__ xe)
{
  int row = blockIdx.x;                // 0..E*M_-1  == (e*B+b)*C + c
  int t = slot_token[row];
  int col = threadIdx.x * 4;
  ushort4 o;
  if (t >= 0) {
    float4 v = *(const float4*)(x + (size_t)t * D_ + col);
    o.x = f2bf(v.x); o.y = f2bf(v.y); o.z = f2bf(v.z); o.w = f2bf(v.w);
  } else {
    o.x = 0; o.y = 0; o.z = 0; o.w = 0;
  }
  *(ushort4*)(xe + (size_t)row * D_ + col) = o;
}

// ---------------------------------------------------------------------------
// K4: transpose+cast weights: in fp32 [E][R][Cc] -> out bf16 [E][Cc][R].
// 64x64 tile; coalesced reads/writes; LDS padded to 65.
// ---------------------------------------------------------------------------
__global__ __launch_bounds__(256) void transcast_kernel(
    const float* __restrict__ in, unsigned short* __restrict__ out, int R, int Cc)
{
  int e = blockIdx.z;
  const float* pin = in + (size_t)e * R * Cc;
  unsigned short* pout = out + (size_t)e * R * Cc;
  __shared__ float T[64][65];
  int r0 = blockIdx.y * 64, c0 = blockIdx.x * 64;
  {
    int row = threadIdx.x >> 2;               // 0..63
    int cb  = (threadIdx.x & 3) * 4;          // 0,4,8,12
#pragma unroll
    for (int p = 0; p < 4; p++) {
      int col = cb + p * 16;
      float4 v = *(const float4*)(pin + (size_t)(r0 + row) * Cc + c0 + col);
      T[row][col+0] = v.x; T[row][col+1] = v.y; T[row][col+2] = v.z; T[row][col+3] = v.w;
    }
  }
  __syncthreads();
  {
    int ocb = threadIdx.x >> 4;               // 0..15
    int or4 = (threadIdx.x & 15) * 4;         // 0..60
#pragma unroll
    for (int p = 0; p < 4; p++) {
      int oc = ocb + p * 16;
      ushort4 o;
      o.x = f2bf(T[or4+0][oc]); o.y = f2bf(T[or4+1][oc]);
      o.z = f2bf(T[or4+2][oc]); o.w = f2bf(T[or4+3][oc]);
      *(ushort4*)(pout + (size_t)(c0 + oc) * R + r0 + or4) = o;
    }
  }
}

// ---------------------------------------------------------------------------
// K5: grouped GEMM, 256x256 8-phase template (T1+T2+T3+T4+T5, m201 structure).
//
// Geometry: BM=BN=256, BK=64, 512 threads = 8 waves (2M x 4N), per-wave
// output 128x64, acc[8][4] f32x4. LDS = 2 dbuf x (A[256][64] + B[256][64])
// bf16 = 128 KiB -> 1 block/CU, 2 waves/SIMD.
//
// T2 swizzle: within a row (128 B = 8 chunks of 16 B), chunk' = chunk ^ (row&7).
// Fragment reads then hit all 32 banks uniformly (8 lanes x 4 banks each, 8 cy
// = b128 minimum). Realized via pre-swizzled GLOBAL source addrs (m173) since
// global_load_lds writes linearly; read side applies the same XOR.
//
// T3/T4 pipeline (counted vmcnt, never 0 in steady state):
//   tile T's A halves issued in ph3 of iter T-2; B halves in ph0/ph1 of iter
//   T-1; single s_waitcnt vmcnt(4) at end of ph3 (tile T+2's A still in
//   flight) before the barrier that opens iter T.
// Phases per K-tile (each: ds_read | stage-issue | bar | lgkmcnt(0) | 16 MFMA | bar):
//   ph0: read A(m0-3,kk01)+B(n0-1,kk01), stage B-half0(t+1) -> mfma m0-3 x n0-1
//   ph1: read B(n2-3,kk01),              stage B-half1(t+1) -> mfma m0-3 x n2-3
//   ph2: read A(m4-7,kk01)                                  -> mfma m4-7 x n2-3
//   ph3: (no reads)                      stage A-halves(t+2) -> mfma m4-7 x n0-1
// K-accumulation order identical to the previous kernel (bitwise-same output).
//
// T1: expert = blockIdx.x & 7 == XCD id (m09 round-robin); n-outer/m-inner.
// EPI=0: h = gelu(acc + b1) -> bf16 Hout [E][M][Nn]
// EPI=1: out[token][col] = gate * (acc + b2), scattered via slot_token
// ---------------------------------------------------------------------------
template<int EPI>
__global__ __launch_bounds__(512, 2) void gemm_kernel(
    const unsigned short* __restrict__ A,    // [E][M][K] bf16
    const unsigned short* __restrict__ BT,   // [E][Nn][K] bf16
    const float* __restrict__ bias,          // [E][Nn] fp32
    unsigned short* __restrict__ Hout,       // EPI=0
    float* __restrict__ Out,                 // EPI=1 (pre-zeroed d_out)
    const int* __restrict__ slot_token,      // EPI=1
    const float* __restrict__ gate_buf,      // EPI=1
    int M, int K, int Nn, int MT)            // MT = M/256 tiles
{
  int e  = blockIdx.x & 7;                  // expert == XCD (round-robin map)
  int s  = blockIdx.x >> 3;                 // slot within expert
  int m0 = (s % MT) * 256;                  // m-inner
  int n0 = (s / MT) * 256;                  // n-outer
  const unsigned short* Ae = A  + (size_t)e * M  * K;
  const unsigned short* Be = BT + (size_t)e * Nn * K;

  __shared__ __align__(16) unsigned short As[2][256 * 64];   // 64 KiB
  __shared__ __align__(16) unsigned short Bs[2][256 * 64];   // 64 KiB
  __shared__ int   s_tok[256];
  __shared__ float s_gate[256];

  int tid  = threadIdx.x;
  int lane = tid & 63;
  int w    = tid >> 6;                      // wave 0..7
  int wm   = (w >> 2) * 128;                // wave row base within tile
  int wn   = (w & 3) * 64;                  // wave col base within tile
  int lr   = lane & 15;
  int quad = lane >> 4;
  // swizzled read chunk offsets (elements) for kk=0 / kk=1
  int c0 = (((quad    ) ^ (lane & 7)) << 3);
  int c1 = (((quad + 4) ^ (lane & 7)) << 3);

  if constexpr (EPI == 1) {
    if (tid < 256) {
      int t = slot_token[(size_t)e * M + m0 + tid];
      s_tok[tid]  = t;
      s_gate[tid] = (t >= 0) ? gate_buf[t] : 0.f;
    }
  }

  floatx4 acc[8][4];
#pragma unroll
  for (int i = 0; i < 8; i++)
#pragma unroll
    for (int j = 0; j < 4; j++) acc[i][j] = (floatx4){0.f, 0.f, 0.f, 0.f};

  // Staging: per operand per K-tile = 256 rows x 64 k = 32 KiB = 2 halves x
  // (8 waves x 2 slots x 1024 B). Slot (w,q) covers rows base..base+8,
  // lane -> row base + (lane>>3), src chunk = (lane&7) ^ (row&7)  [inverse
  // swizzle; row&7 == lane>>3 since base % 8 == 0]. LDS dest linear.
  int rrow = lane >> 3;
  int sch  = ((lane & 7) ^ rrow) << 3;      // source chunk offset in elements
  const unsigned short* gA00 = Ae + (size_t)(m0       + w*16     + rrow) * K + sch;
  const unsigned short* gA01 = Ae + (size_t)(m0       + w*16 + 8 + rrow) * K + sch;
  const unsigned short* gA10 = Ae + (size_t)(m0 + 128 + w*16     + rrow) * K + sch;
  const unsigned short* gA11 = Ae + (size_t)(m0 + 128 + w*16 + 8 + rrow) * K + sch;
  const unsigned short* gB00 = Be + (size_t)(n0       + w*16     + rrow) * K + sch;
  const unsigned short* gB01 = Be + (size_t)(n0       + w*16 + 8 + rrow) * K + sch;
  const unsigned short* gB10 = Be + (size_t)(n0 + 128 + w*16     + rrow) * K + sch;
  const unsigned short* gB11 = Be + (size_t)(n0 + 128 + w*16 + 8 + rrow) * K + sch;

#define STAGE_A0(dbuf) do { \
    gload_lds16(gA00, &As[dbuf][(w*16    ) * 64]); \
    gload_lds16(gA01, &As[dbuf][(w*16 + 8) * 64]); \
    gA00 += 64; gA01 += 64; } while (0)
#define STAGE_A1(dbuf) do { \
    gload_lds16(gA10, &As[dbuf][(128 + w*16    ) * 64]); \
    gload_lds16(gA11, &As[dbuf][(128 + w*16 + 8) * 64]); \
    gA10 += 64; gA11 += 64; } while (0)
#define STAGE_B0(dbuf) do { \
    gload_lds16(gB00, &Bs[dbuf][(w*16    ) * 64]); \
    gload_lds16(gB01, &Bs[dbuf][(w*16 + 8) * 64]); \
    gB00 += 64; gB01 += 64; } while (0)
#define STAGE_B1(dbuf) do { \
    gload_lds16(gB10, &Bs[dbuf][(128 + w*16    ) * 64]); \
    gload_lds16(gB11, &Bs[dbuf][(128 + w*16 + 8) * 64]); \
    gB10 += 64; gB11 += 64; } while (0)

  int nt = K >> 6;                          // K-tiles of 64
  // Prologue: tile0 fully into buf0; tile1 A-halves into buf1; wait tile0.
  STAGE_A0(0); STAGE_A1(0); STAGE_B0(0); STAGE_B1(0);
  if (nt > 1) {
    STAGE_A0(1); STAGE_A1(1);
    asm volatile("s_waitcnt vmcnt(4)" ::: "memory");
  } else {
    asm volatile("s_waitcnt vmcnt(0)" ::: "memory");
  }
  __builtin_amdgcn_s_barrier();

  short8 af[4][2], bf[4][2];
  int cur = 0;
  for (int t = 0; t < nt; ++t) {
    int nxt = cur ^ 1;
    // ---------------- phase 0 ----------------
#pragma unroll
    for (int m = 0; m < 4; ++m) {
      int row = wm + m * 16 + lr;
      af[m][0] = *(const short8*)&As[cur][row * 64 + c0];
      af[m][1] = *(const short8*)&As[cur][row * 64 + c1];
    }
#pragma unroll
    for (int n = 0; n < 2; ++n) {
      int row = wn + n * 16 + lr;
      bf[n][0] = *(const short8*)&Bs[cur][row * 64 + c0];
      bf[n][1] = *(const short8*)&Bs[cur][row * 64 + c1];
    }
    if (t + 1 < nt) STAGE_B0(nxt);
    __builtin_amdgcn_s_barrier();
    asm volatile("s_waitcnt lgkmcnt(0)" ::: "memory");
    __builtin_amdgcn_sched_barrier(0);
    __builtin_amdgcn_s_setprio(1);
#pragma unroll
    for (int m = 0; m < 4; ++m)
#pragma unroll
      for (int n = 0; n < 2; ++n) {
        acc[m][n] = __builtin_amdgcn_mfma_f32_16x16x32_bf16(af[m][0], bf[n][0], acc[m][n], 0, 0, 0);
        acc[m][n] = __builtin_amdgcn_mfma_f32_16x16x32_bf16(af[m][1], bf[n][1], acc[m][n], 0, 0, 0);
      }
    __builtin_amdgcn_s_setprio(0);
    __builtin_amdgcn_s_barrier();
    // ---------------- phase 1 ----------------
#pragma unroll
    for (int n = 0; n < 2; ++n) {
      int row = wn + (n + 2) * 16 + lr;
      bf[n+2][0] = *(const short8*)&Bs[cur][row * 64 + c0];
      bf[n+2][1] = *(const short8*)&Bs[cur][row * 64 + c1];
    }
    if (t + 1 < nt) STAGE_B1(nxt);
    __builtin_amdgcn_s_barrier();
    asm volatile("s_waitcnt lgkmcnt(0)" ::: "memory");
    __builtin_amdgcn_sched_barrier(0);
    __builtin_amdgcn_s_setprio(1);
#pragma unroll
    for (int m = 0; m < 4; ++m)
#pragma unroll
      for (int n = 2; n < 4; ++n) {
        acc[m][n] = __builtin_amdgcn_mfma_f32_16x16x32_bf16(af[m][0], bf[n][0], acc[m][n], 0, 0, 0);
        acc[m][n] = __builtin_amdgcn_mfma_f32_16x16x32_bf16(af[m][1], bf[n][1], acc[m][n], 0, 0, 0);
      }
    __builtin_amdgcn_s_setprio(0);
    __builtin_amdgcn_s_barrier();
    // ---------------- phase 2 ----------------
#pragma unroll
    for (int m = 0; m < 4; ++m) {
      int row = wm + 64 + m * 16 + lr;
      af[m][0] = *(const short8*)&As[cur][row * 64 + c0];
      af[m][1] = *(const short8*)&As[cur][row * 64 + c1];
    }
    __builtin_amdgcn_s_barrier();
    asm volatile("s_waitcnt lgkmcnt(0)" ::: "memory");
    __builtin_amdgcn_sched_barrier(0);
    __builtin_amdgcn_s_setprio(1);
#pragma unroll
    for (int m = 0; m < 4; ++m)
#pragma unroll
      for (int n = 2; n < 4; ++n) {
        acc[m+4][n] = __builtin_amdgcn_mfma_f32_16x16x32_bf16(af[m][0], bf[n][0], acc[m+4][n], 0, 0, 0);
        acc[m+4][n] = __builtin_amdgcn_mfma_f32_16x16x32_bf16(af[m][1], bf[n][1], acc[m+4][n], 0, 0, 0);
      }
    __builtin_amdgcn_s_setprio(0);
    __builtin_amdgcn_s_barrier();
    // ---------------- phase 3 ----------------
    // A region of buf[cur] fully consumed (ph2 reads complete before its end
    // barrier) -> safe to begin staging tile t+2's A halves into buf[cur].
    if (t + 2 < nt) { STAGE_A0(cur); STAGE_A1(cur); }
    __builtin_amdgcn_s_barrier();
    __builtin_amdgcn_s_setprio(1);
#pragma unroll
    for (int m = 0; m < 4; ++m)
#pragma unroll
      for (int n = 0; n < 2; ++n) {
        acc[m+4][n] = __builtin_amdgcn_mfma_f32_16x16x32_bf16(af[m][0], bf[n][0], acc[m+4][n], 0, 0, 0);
        acc[m+4][n] = __builtin_amdgcn_mfma_f32_16x16x32_bf16(af[m][1], bf[n][1], acc[m+4][n], 0, 0, 0);
      }
    __builtin_amdgcn_s_setprio(0);
    // Counted wait: tile t+1 (oldest 8 loads) must have landed; tile t+2's
    // 4 A-loads stay in flight. Then the barrier publishes across waves.
    if (t + 1 < nt) {
      if (t + 2 < nt) asm volatile("s_waitcnt vmcnt(4)" ::: "memory");
      else            asm volatile("s_waitcnt vmcnt(0)" ::: "memory");
    }
    __builtin_amdgcn_s_barrier();
    cur = nxt;
  }
#undef STAGE_A0
#undef STAGE_A1
#undef STAGE_B0
#undef STAGE_B1

  // Epilogue. C/D layout: col = lane&15, row = quad*4 + reg (m89-verified).
#pragma unroll
  for (int m = 0; m < 8; ++m) {
    int rloc = wm + m * 16 + quad * 4;      // block-local row base
#pragma unroll
    for (int n = 0; n < 4; ++n) {
      int col = n0 + wn + n * 16 + lr;
      float bz = bias[(size_t)e * Nn + col];
      if constexpr (EPI == 0) {
        size_t base = (size_t)e * M * Nn + (size_t)(m0 + rloc) * Nn + col;
#pragma unroll
        for (int r = 0; r < 4; r++)
          Hout[base + (size_t)r * Nn] = f2bf(gelu_fast(acc[m][n][r] + bz));
      } else {
#pragma unroll
        for (int r = 0; r < 4; r++) {
          int t = s_tok[rloc + r];
          if (t >= 0)
            Out[(size_t)t * D_ + col] = s_gate[rloc + r] * (acc[m][n][r] + bz);
        }
      }
    }
  }
}

// ---------------------------------------------------------------------------
extern "C" void kernel_launch(void* const* d_in, const int* in_sizes, int n_in,
                              void* d_out, int out_size, void* d_ws, size_t ws_size,
                              hipStream_t stream)
{
  (void)in_sizes; (void)n_in; (void)ws_size;
  const float* x  = (const float*)d_in[0];
  const float* wr = (const float*)d_in[1];
  const float* w1 = (const float*)d_in[2];
  const float* b1 = (const float*)d_in[3];
  const float* w2 = (const float*)d_in[4];
  const float* b2 = (const float*)d_in[5];
  float* out = (float*)d_out;

  // ws layout (~172 MB total)
  char* ws = (char*)d_ws;
  int*   idx_buf  = (int*)(ws + 0);              // 32 KB
  float* gate_buf = (float*)(ws + 32768);        // 32 KB
  float* stats    = (float*)(ws + 65536);        // 1 KB
  int*   slot_tok = (int*)(ws + 66560);          // 40 KB
  unsigned short* xe  = (unsigned short*)(ws + 107520);    // 20.97 MB
  unsigned short* wbf = (unsigned short*)(ws + 21079040);  // 67.1 MB (w1 then w2)
  unsigned short* hbf = (unsigned short*)(ws + 88187904);  // 83.9 MB; end 172073984

  hipMemsetAsync(d_out, 0, (size_t)out_size * 4, stream);       // dropped tokens -> 0
  hipMemsetAsync(stats, 0, 1024, stream);
  hipMemsetAsync(slot_tok, 0xFF, (size_t)E_ * B_ * C_ * 4, stream);  // -1 = empty slot

  router_kernel<<<(B_ * N_) / 4, 256, 0, stream>>>(x, wr, idx_buf, gate_buf, stats);
  pos_kernel<<<B_ * E_, 64, 0, stream>>>(idx_buf, slot_tok, stats,
                                         out + (size_t)B_ * N_ * D_);
  gather_kernel<<<E_ * M_, 256, 0, stream>>>(x, slot_tok, xe);

  // w1 [E][D][H] -> wbf [E][H][D]
  transcast_kernel<<<dim3(H_ / 64, D_ / 64, E_), 256, 0, stream>>>(w1, wbf, D_, H_);
  // h = gelu(xe @ w1 + b1): M=1280, K=1024, Nn=4096; grid = E * (16n x 5m), 512 thr
  gemm_kernel<0><<<E_ * (H_ / 256) * (M_ / 256), 512, 0, stream>>>(
      xe, wbf, b1, hbf, nullptr, nullptr, nullptr, M_, D_, H_, M_ / 256);
  // w2 [E][H][D] -> wbf [E][D][H]  (reuse buffer; stream-serialized after GEMM1)
  transcast_kernel<<<dim3(D_ / 64, H_ / 64, E_), 256, 0, stream>>>(w2, wbf, H_, D_);
  // out = gate * (h @ w2 + b2): M=1280, K=4096, Nn=1024; grid = E * (4n x 5m)
  gemm_kernel<1><<<E_ * (D_ / 256) * (M_ / 256), 512, 0, stream>>>(
      hbf, wbf, b2, nullptr, out, slot_tok, gate_buf, M_, H_, D_, M_ / 256);
}

// Round 2
// 660.971 us; speedup vs baseline: 1.0066x; 1.0066x over previous
//
#include <hip/hip_runtime.h>
#include <hip/hip_bf16.h>
#include <math.h>

// Problem constants (B=4, N=2048, D=1024, E=8, H=4096, C = int(2048*1.25//8)=320)
#define B_ 4
#define N_ 2048
#define D_ 1024
#define E_ 8
#define H_ 4096
#define C_ 320
#define M_ (B_*C_)        // 1280 rows per expert in the grouped GEMMs

typedef __attribute__((ext_vector_type(8))) short short8;   // 8 bf16 = 4 VGPRs (MFMA A/B frag)
typedef __attribute__((ext_vector_type(4))) float floatx4;  // MFMA C/D frag

__device__ __forceinline__ unsigned short f2bf(float f) {
  unsigned u = __builtin_bit_cast(unsigned, f);
  u += 0x7fffu + ((u >> 16) & 1u);          // RNE; inputs are tame (no NaN/Inf)
  return (unsigned short)(u >> 16);
}

// fast tanh-gelu via v_exp_f32: tanh(u) = 1 - 2/(exp(2u)+1). |err| ~1e-6, buried by bf16.
__device__ __forceinline__ float gelu_fast(float x) {
  float u = 0.7978845608028654f * (x + 0.044715f * x * x * x);
  float t = 1.f - 2.f / (__expf(2.f * u) + 1.f);
  return 0.5f * x * (1.f + t);
}

// async global -> LDS, 16 B per lane. LDS dest = wave-uniform base + lane*16 (m97/m104).
__device__ __forceinline__ void gload_lds16(const unsigned short* g, unsigned short* l) {
  __builtin_amdgcn_global_load_lds(
      (const __attribute__((address_space(1))) unsigned int*)g,
      (__attribute__((address_space(3))) unsigned int*)l, 16, 0, 0);
}

// ---------------------------------------------------------------------------
// K1: router. One wave per token; fp64 accumulation to avoid argmax flips vs
// the numpy fp32 reference. stats: [0..31]=count[b*8+e], [32..63]=proxy, [64]=z^2 sum
// ---------------------------------------------------------------------------
__global__ __launch_bounds__(256) void router_kernel(
    const float* __restrict__ x, const float* __restrict__ wr,
    int* __restrict__ idx_buf, float* __restrict__ gate_buf,
    float* __restrict__ stats)
{
  int lane  = threadIdx.x & 63;
  int wave  = threadIdx.x >> 6;
  int token = blockIdx.x * 4 + wave;        // 0..8191
  int b     = token >> 11;                  // N_=2048

  const float* xp = x + (size_t)token * D_ + lane * 16;
  float xv[16];
#pragma unroll
  for (int i = 0; i < 4; i++) {
    float4 v = ((const float4*)xp)[i];
    xv[i*4+0]=v.x; xv[i*4+1]=v.y; xv[i*4+2]=v.z; xv[i*4+3]=v.w;
  }
  double acc[8];
#pragma unroll
  for (int e = 0; e < 8; e++) acc[e] = 0.0;
  const float* wp = wr + (size_t)(lane * 16) * E_;   // w_router is [D][E]
#pragma unroll
  for (int i = 0; i < 16; i++) {
    float xs = xv[i];
#pragma unroll
    for (int e = 0; e < 8; e++) acc[e] += (double)xs * (double)wp[i*8 + e];
  }
  for (int off = 32; off > 0; off >>= 1) {
#pragma unroll
    for (int e = 0; e < 8; e++) acc[e] += __shfl_xor(acc[e], off, 64);
  }

  float l[8];
#pragma unroll
  for (int e = 0; e < 8; e++) l[e] = (float)acc[e];
  float m = l[0]; int best = 0;
#pragma unroll
  for (int e = 1; e < 8; e++) if (l[e] > m) { m = l[e]; best = e; }   // first-max tiebreak
  float p[8], sum = 0.f;
#pragma unroll
  for (int e = 0; e < 8; e++) { p[e] = expf(l[e] - m); sum += p[e]; }
  float inv = 1.f / sum;
#pragma unroll
  for (int e = 0; e < 8; e++) p[e] *= inv;
  float z    = m + logf(sum);
  float gate = inv;                      // softmax at argmax = exp(0)/sum

  __shared__ float s_cnt[8], s_prox[8], s_zsq[1];
  if (threadIdx.x < 8)  { s_cnt[threadIdx.x] = 0.f; s_prox[threadIdx.x] = 0.f; }
  if (threadIdx.x == 8) s_zsq[0] = 0.f;
  __syncthreads();
  if (lane == 0) {
    idx_buf[token]  = best;
    gate_buf[token] = gate;
    atomicAdd(&s_zsq[0], z * z);
    atomicAdd(&s_cnt[best], 1.f);
#pragma unroll
    for (int e = 0; e < 8; e++) atomicAdd(&s_prox[e], p[e]);
  }
  __syncthreads();
  if (threadIdx.x < 8) {
    atomicAdd(&stats[b*8 + threadIdx.x],      s_cnt[threadIdx.x]);
    atomicAdd(&stats[32 + b*8 + threadIdx.x], s_prox[threadIdx.x]);
  }
  if (threadIdx.x == 8) atomicAdd(&stats[64], s_zsq[0]);
}

// ---------------------------------------------------------------------------
// K2: per-(b,e) capacity scan + loss finalize (folded; stats ready since the
// router kernel completed before this launch).
// ---------------------------------------------------------------------------
__global__ __launch_bounds__(64) void pos_kernel(
    const int* __restrict__ idx_buf, int* __restrict__ slot_token,
    const float* __restrict__ stats, float* __restrict__ loss_out)
{
  int be = blockIdx.x;                 // 0..31
  int b = be >> 3, e = be & 7;
  int lane = threadIdx.x;
  int base = 0;
  int* out = slot_token + (size_t)(e * B_ + b) * C_;
  for (int n0 = 0; n0 < N_; n0 += 64) {
    int n = n0 + lane;
    bool match = (idx_buf[b * N_ + n] == e);
    unsigned long long mask = __ballot(match);
    int my = base + __popcll(mask & ((1ull << lane) - 1ull));
    if (match && my < C_) out[my] = b * N_ + n;
    base += __popcll(mask);
  }
  if (be == 0 && lane == 0) {
    float aux = 0.f;
    for (int i = 0; i < 32; i++) aux += stats[i] * stats[32 + i];
    aux *= 64.f / ((float)B_ * (float)N_ * (float)N_);   // E^2 / (B*N*N)
    loss_out[0] = aux;
    loss_out[1] = stats[64] / (float)(B_ * N_);
  }
}

// ---------------------------------------------------------------------------
// K3: gather+cast x rows into xe bf16 [E][M_][D]. One block per slot row.
// ---------------------------------------------------------------------------
__global__ __launch_bounds__(256) void gather_kernel(
    const float* __restrict__ x, const int* __restrict__ slot_token,
    unsigned short* __restrict__ xe)
{
  int row = blockIdx.x;                // 0..E*M_-1  == (e*B+b)*C + c
  int t = slot_token[row];
  int col = threadIdx.x * 4;
  ushort4 o;
  if (t >= 0) {
    float4 v = *(const float4*)(x + (size_t)t * D_ + col);
    o.x = f2bf(v.x); o.y = f2bf(v.y); o.z = f2bf(v.z); o.w = f2bf(v.w);
  } else {
    o.x = 0; o.y = 0; o.z = 0; o.w = 0;
  }
  *(ushort4*)(xe + (size_t)row * D_ + col) = o;
}

// ---------------------------------------------------------------------------
// K4: transpose+cast weights: in fp32 [E][R][Cc] -> out bf16 [E][Cc][R].
// 64x64 tile; coalesced reads/writes; LDS padded to 65.
// ---------------------------------------------------------------------------
__global__ __launch_bounds__(256) void transcast_kernel(
    const float* __restrict__ in, unsigned short* __restrict__ out, int R, int Cc)
{
  int e = blockIdx.z;
  const float* pin = in + (size_t)e * R * Cc;
  unsigned short* pout = out + (size_t)e * R * Cc;
  __shared__ float T[64][65];
  int r0 = blockIdx.y * 64, c0 = blockIdx.x * 64;
  {
    int row = threadIdx.x >> 2;               // 0..63
    int cb  = (threadIdx.x & 3) * 4;          // 0,4,8,12
#pragma unroll
    for (int p = 0; p < 4; p++) {
      int col = cb + p * 16;
      float4 v = *(const float4*)(pin + (size_t)(r0 + row) * Cc + c0 + col);
      T[row][col+0] = v.x; T[row][col+1] = v.y; T[row][col+2] = v.z; T[row][col+3] = v.w;
    }
  }
  __syncthreads();
  {
    int ocb = threadIdx.x >> 4;               // 0..15
    int or4 = (threadIdx.x & 15) * 4;         // 0..60
#pragma unroll
    for (int p = 0; p < 4; p++) {
      int oc = ocb + p * 16;
      ushort4 o;
      o.x = f2bf(T[or4+0][oc]); o.y = f2bf(T[or4+1][oc]);
      o.z = f2bf(T[or4+2][oc]); o.w = f2bf(T[or4+3][oc]);
      *(ushort4*)(pout + (size_t)(c0 + oc) * R + r0 + or4) = o;
    }
  }
}

// ---------------------------------------------------------------------------
// K5: grouped GEMM, 256x256 8-phase (T1+T2+T3+T4+T5), DEEP pipeline (R2):
// uniform 2-K-tile prefetch lead for BOTH operands, steady-state wait
// vmcnt(8) (tile t+2's 8 loads stay in flight; t+1's, issued a full
// iteration earlier, are drained). R1's B-lead was only ~0.5 tile -> all 8
// waves piled on the end-of-iter wait (MfmaUtil 21%, VALUBusy 9.5%).
//
// Staging for tile t+2 is folded into phases 2-3 of iter t, into buf[cur]
// as it is vacated:
//   B[cur] reads all complete before ph1-end barrier -> ph2 stages B(t+2).
//   A[cur] reads all complete before ph2-end barrier -> ph3 stages A(t+2).
// Per-phase: {ds_read frags | stage-issue | bar | lgkmcnt(0) | 16 MFMA | bar}.
// MFMA issue order identical to R1 (bitwise-same output).
//
// T2 swizzle (verified R1: SQ_LDS_BANK_CONFLICT = 0): chunk' = chunk^(row&7),
// realized via pre-swizzled GLOBAL source addrs (LDS dest linear, m104/m173);
// read side applies the same XOR.
// ---------------------------------------------------------------------------
template<int EPI>
__global__ __launch_bounds__(512, 2) void gemm_kernel(
    const unsigned short* __restrict__ A,    // [E][M][K] bf16
    const unsigned short* __restrict__ BT,   // [E][Nn][K] bf16
    const float* __restrict__ bias,          // [E][Nn] fp32
    unsigned short* __restrict__ Hout,       // EPI=0
    float* __restrict__ Out,                 // EPI=1 (pre-zeroed d_out)
    const int* __restrict__ slot_token,      // EPI=1
    const float* __restrict__ gate_buf,      // EPI=1
    int M, int K, int Nn, int MT)            // MT = M/256 tiles
{
  int e  = blockIdx.x & 7;                  // expert == XCD (round-robin map)
  int s  = blockIdx.x >> 3;                 // slot within expert
  int m0 = (s % MT) * 256;                  // m-inner
  int n0 = (s / MT) * 256;                  // n-outer
  const unsigned short* Ae = A  + (size_t)e * M  * K;
  const unsigned short* Be = BT + (size_t)e * Nn * K;

  __shared__ __align__(16) unsigned short As[2][256 * 64];   // 64 KiB
  __shared__ __align__(16) unsigned short Bs[2][256 * 64];   // 64 KiB
  __shared__ int   s_tok[256];
  __shared__ float s_gate[256];

  int tid  = threadIdx.x;
  int lane = tid & 63;
  int w    = tid >> 6;                      // wave 0..7
  int wm   = (w >> 2) * 128;                // wave row base within tile
  int wn   = (w & 3) * 64;                  // wave col base within tile
  int lr   = lane & 15;
  int quad = lane >> 4;
  // swizzled read chunk offsets (elements) for kk=0 / kk=1
  int c0 = (((quad    ) ^ (lane & 7)) << 3);
  int c1 = (((quad + 4) ^ (lane & 7)) << 3);

  if constexpr (EPI == 1) {
    if (tid < 256) {
      int t = slot_token[(size_t)e * M + m0 + tid];
      s_tok[tid]  = t;
      s_gate[tid] = (t >= 0) ? gate_buf[t] : 0.f;
    }
  }

  floatx4 acc[8][4];
#pragma unroll
  for (int i = 0; i < 8; i++)
#pragma unroll
    for (int j = 0; j < 4; j++) acc[i][j] = (floatx4){0.f, 0.f, 0.f, 0.f};

  // Staging: per operand per K-tile = 256 rows x 64 k = 32 KiB = 2 halves x
  // (8 waves x 2 slots x 1024 B). Lane -> row base + (lane>>3),
  // src chunk = (lane&7) ^ (row&7) [inverse swizzle]. LDS dest linear.
  int rrow = lane >> 3;
  int sch  = ((lane & 7) ^ rrow) << 3;      // source chunk offset in elements
  const unsigned short* gA00 = Ae + (size_t)(m0       + w*16     + rrow) * K + sch;
  const unsigned short* gA01 = Ae + (size_t)(m0       + w*16 + 8 + rrow) * K + sch;
  const unsigned short* gA10 = Ae + (size_t)(m0 + 128 + w*16     + rrow) * K + sch;
  const unsigned short* gA11 = Ae + (size_t)(m0 + 128 + w*16 + 8 + rrow) * K + sch;
  const unsigned short* gB00 = Be + (size_t)(n0       + w*16     + rrow) * K + sch;
  const unsigned short* gB01 = Be + (size_t)(n0       + w*16 + 8 + rrow) * K + sch;
  const unsigned short* gB10 = Be + (size_t)(n0 + 128 + w*16     + rrow) * K + sch;
  const unsigned short* gB11 = Be + (size_t)(n0 + 128 + w*16 + 8 + rrow) * K + sch;

#define STAGE_A(dbuf) do { \
    gload_lds16(gA00, &As[dbuf][(w*16    ) * 64]); \
    gload_lds16(gA01, &As[dbuf][(w*16 + 8) * 64]); \
    gload_lds16(gA10, &As[dbuf][(128 + w*16    ) * 64]); \
    gload_lds16(gA11, &As[dbuf][(128 + w*16 + 8) * 64]); \
    gA00 += 64; gA01 += 64; gA10 += 64; gA11 += 64; } while (0)
#define STAGE_B(dbuf) do { \
    gload_lds16(gB00, &Bs[dbuf][(w*16    ) * 64]); \
    gload_lds16(gB01, &Bs[dbuf][(w*16 + 8) * 64]); \
    gload_lds16(gB10, &Bs[dbuf][(128 + w*16    ) * 64]); \
    gload_lds16(gB11, &Bs[dbuf][(128 + w*16 + 8) * 64]); \
    gB00 += 64; gB01 += 64; gB10 += 64; gB11 += 64; } while (0)

  int nt = K >> 6;                          // K-tiles of 64
  // Prologue: t0 -> buf0 and t1 -> buf1 fully; wait t0 (t1's 8 stay in flight).
  STAGE_A(0); STAGE_B(0);
  if (nt > 1) {
    STAGE_A(1); STAGE_B(1);
    asm volatile("s_waitcnt vmcnt(8)" ::: "memory");
  } else {
    asm volatile("s_waitcnt vmcnt(0)" ::: "memory");
  }
  __builtin_amdgcn_s_barrier();

  short8 af[4][2], bf[4][2];
  int cur = 0;
  for (int t = 0; t < nt; ++t) {
    int nxt = cur ^ 1;
    bool pf = (t + 2 < nt);
    // ---------------- phase 0: read A(m0-3), B(n0-1) ----------------
#pragma unroll
    for (int m = 0; m < 4; ++m) {
      int row = wm + m * 16 + lr;
      af[m][0] = *(const short8*)&As[cur][row * 64 + c0];
      af[m][1] = *(const short8*)&As[cur][row * 64 + c1];
    }
#pragma unroll
    for (int n = 0; n < 2; ++n) {
      int row = wn + n * 16 + lr;
      bf[n][0] = *(const short8*)&Bs[cur][row * 64 + c0];
      bf[n][1] = *(const short8*)&Bs[cur][row * 64 + c1];
    }
    __builtin_amdgcn_s_barrier();
    asm volatile("s_waitcnt lgkmcnt(0)" ::: "memory");
    __builtin_amdgcn_sched_barrier(0);
    __builtin_amdgcn_s_setprio(1);
#pragma unroll
    for (int m = 0; m < 4; ++m)
#pragma unroll
      for (int n = 0; n < 2; ++n) {
        acc[m][n] = __builtin_amdgcn_mfma_f32_16x16x32_bf16(af[m][0], bf[n][0], acc[m][n], 0, 0, 0);
        acc[m][n] = __builtin_amdgcn_mfma_f32_16x16x32_bf16(af[m][1], bf[n][1], acc[m][n], 0, 0, 0);
      }
    __builtin_amdgcn_s_setprio(0);
    __builtin_amdgcn_s_barrier();
    // ---------------- phase 1: read B(n2-3) ----------------
#pragma unroll
    for (int n = 0; n < 2; ++n) {
      int row = wn + (n + 2) * 16 + lr;
      bf[n+2][0] = *(const short8*)&Bs[cur][row * 64 + c0];
      bf[n+2][1] = *(const short8*)&Bs[cur][row * 64 + c1];
    }
    __builtin_amdgcn_s_barrier();
    asm volatile("s_waitcnt lgkmcnt(0)" ::: "memory");
    __builtin_amdgcn_sched_barrier(0);
    __builtin_amdgcn_s_setprio(1);
#pragma unroll
    for (int m = 0; m < 4; ++m)
#pragma unroll
      for (int n = 2; n < 4; ++n) {
        acc[m][n] = __builtin_amdgcn_mfma_f32_16x16x32_bf16(af[m][0], bf[n][0], acc[m][n], 0, 0, 0);
        acc[m][n] = __builtin_amdgcn_mfma_f32_16x16x32_bf16(af[m][1], bf[n][1], acc[m][n], 0, 0, 0);
      }
    __builtin_amdgcn_s_setprio(0);
    __builtin_amdgcn_s_barrier();
    // ---------------- phase 2: read A(m4-7); stage B(t+2) -> Bs[cur] -------
    // (all B[cur] reads completed before the ph1-end barrier -> safe)
#pragma unroll
    for (int m = 0; m < 4; ++m) {
      int row = wm + 64 + m * 16 + lr;
      af[m][0] = *(const short8*)&As[cur][row * 64 + c0];
      af[m][1] = *(const short8*)&As[cur][row * 64 + c1];
    }
    if (pf) STAGE_B(cur);
    __builtin_amdgcn_s_barrier();
    asm volatile("s_waitcnt lgkmcnt(0)" ::: "memory");
    __builtin_amdgcn_sched_barrier(0);
    __builtin_amdgcn_s_setprio(1);
#pragma unroll
    for (int m = 0; m < 4; ++m)
#pragma unroll
      for (int n = 2; n < 4; ++n) {
        acc[m+4][n] = __builtin_amdgcn_mfma_f32_16x16x32_bf16(af[m][0], bf[n][0], acc[m+4][n], 0, 0, 0);
        acc[m+4][n] = __builtin_amdgcn_mfma_f32_16x16x32_bf16(af[m][1], bf[n][1], acc[m+4][n], 0, 0, 0);
      }
    __builtin_amdgcn_s_setprio(0);
    __builtin_amdgcn_s_barrier();
    // ---------------- phase 3: stage A(t+2) -> As[cur] ----------------
    // (all A[cur] reads completed before the ph2-end barrier -> safe)
    if (pf) STAGE_A(cur);
    __builtin_amdgcn_s_barrier();
    __builtin_amdgcn_s_setprio(1);
#pragma unroll
    for (int m = 0; m < 4; ++m)
#pragma unroll
      for (int n = 0; n < 2; ++n) {
        acc[m+4][n] = __builtin_amdgcn_mfma_f32_16x16x32_bf16(af[m][0], bf[n][0], acc[m+4][n], 0, 0, 0);
        acc[m+4][n] = __builtin_amdgcn_mfma_f32_16x16x32_bf16(af[m][1], bf[n][1], acc[m+4][n], 0, 0, 0);
      }
    __builtin_amdgcn_s_setprio(0);
    // Counted wait: t+1's 8 loads (issued in iter t-1) must have landed;
    // t+2's 8 loads (issued this iter) stay in flight. Never drains to 0
    // in steady state.
    if (pf)                asm volatile("s_waitcnt vmcnt(8)" ::: "memory");
    else if (t + 1 < nt)   asm volatile("s_waitcnt vmcnt(0)" ::: "memory");
    __builtin_amdgcn_s_barrier();
    cur = nxt;
  }
#undef STAGE_A
#undef STAGE_B

  // Epilogue. C/D layout: col = lane&15, row = quad*4 + reg (m89-verified).
#pragma unroll
  for (int m = 0; m < 8; ++m) {
    int rloc = wm + m * 16 + quad * 4;      // block-local row base
#pragma unroll
    for (int n = 0; n < 4; ++n) {
      int col = n0 + wn + n * 16 + lr;
      float bz = bias[(size_t)e * Nn + col];
      if constexpr (EPI == 0) {
        size_t base = (size_t)e * M * Nn + (size_t)(m0 + rloc) * Nn + col;
#pragma unroll
        for (int r = 0; r < 4; r++)
          Hout[base + (size_t)r * Nn] = f2bf(gelu_fast(acc[m][n][r] + bz));
      } else {
#pragma unroll
        for (int r = 0; r < 4; r++) {
          int t = s_tok[rloc + r];
          if (t >= 0)
            Out[(size_t)t * D_ + col] = s_gate[rloc + r] * (acc[m][n][r] + bz);
        }
      }
    }
  }
}

// ---------------------------------------------------------------------------
extern "C" void kernel_launch(void* const* d_in, const int* in_sizes, int n_in,
                              void* d_out, int out_size, void* d_ws, size_t ws_size,
                              hipStream_t stream)
{
  (void)in_sizes; (void)n_in; (void)ws_size;
  const float* x  = (const float*)d_in[0];
  const float* wr = (const float*)d_in[1];
  const float* w1 = (const float*)d_in[2];
  const float* b1 = (const float*)d_in[3];
  const float* w2 = (const float*)d_in[4];
  const float* b2 = (const float*)d_in[5];
  float* out = (float*)d_out;

  // ws layout (~172 MB total)
  char* ws = (char*)d_ws;
  int*   idx_buf  = (int*)(ws + 0);              // 32 KB
  float* gate_buf = (float*)(ws + 32768);        // 32 KB
  float* stats    = (float*)(ws + 65536);        // 1 KB
  int*   slot_tok = (int*)(ws + 66560);          // 40 KB
  unsigned short* xe  = (unsigned short*)(ws + 107520);    // 20.97 MB
  unsigned short* wbf = (unsigned short*)(ws + 21079040);  // 67.1 MB (w1 then w2)
  unsigned short* hbf = (unsigned short*)(ws + 88187904);  // 83.9 MB; end 172073984

  hipMemsetAsync(d_out, 0, (size_t)out_size * 4, stream);       // dropped tokens -> 0
  hipMemsetAsync(stats, 0, 1024, stream);
  hipMemsetAsync(slot_tok, 0xFF, (size_t)E_ * B_ * C_ * 4, stream);  // -1 = empty slot

  router_kernel<<<(B_ * N_) / 4, 256, 0, stream>>>(x, wr, idx_buf, gate_buf, stats);
  pos_kernel<<<B_ * E_, 64, 0, stream>>>(idx_buf, slot_tok, stats,
                                         out + (size_t)B_ * N_ * D_);
  gather_kernel<<<E_ * M_, 256, 0, stream>>>(x, slot_tok, xe);

  // w1 [E][D][H] -> wbf [E][H][D]
  transcast_kernel<<<dim3(H_ / 64, D_ / 64, E_), 256, 0, stream>>>(w1, wbf, D_, H_);
  // h = gelu(xe @ w1 + b1): M=1280, K=1024, Nn=4096; grid = E * (16n x 5m), 512 thr
  gemm_kernel<0><<<E_ * (H_ / 256) * (M_ / 256), 512, 0, stream>>>(
      xe, wbf, b1, hbf, nullptr, nullptr, nullptr, M_, D_, H_, M_ / 256);
  // w2 [E][H][D] -> wbf [E][D][H]  (reuse buffer; stream-serialized after GEMM1)
  transcast_kernel<<<dim3(D_ / 64, H_ / 64, E_), 256, 0, stream>>>(w2, wbf, H_, D_);
  // out = gate * (h @ w2 + b2): M=1280, K=4096, Nn=1024; grid = E * (4n x 5m)
  gemm_kernel<1><<<E_ * (D_ / 256) * (M_ / 256), 512, 0, stream>>>(
      hbf, wbf, b2, nullptr, out, slot_tok, gate_buf, M_, H_, D_, M_ / 256);
}